// Round 21
// baseline (162.730 us; speedup 1.0000x reference)
//
#include <hip/hip_runtime.h>

// CentroidPool: argmin_k ||x_i - c_k||^2, N=131072, K=1024, D=128, fp32.
// = argmin_k (0.5||c_k||^2 - x.c_k).
// 2-term fp16 latent split (sound eps_row = 0.0028*||x||+0.015); certify-
// or-recompute: flagged rows -> exact fp32 pass B.
// r20 postmortem: reorder null; pass A stall = only 6.5 waves/CU (20.5KB
// LDS) with 33% dead cycles. r21: grp=2 (32 rows/wave, 64 frag regs ->
// launch_bounds(64,4) no-spill), KT=16 (4KB tiles -> 12KB LDS -> 13
// blocks/CU = 41% occ), c2 acc-init prefetched into registers a tile
// ahead. Same total MFMA work; 2x waves to hide the per-tile holes.
// Pass A: 1 wave/block, wave-private LDS dbuf, ZERO barriers, vmcnt(4).

constexpr int N = 131072;
constexpr int K = 1024;
constexpr int D = 128;

typedef __attribute__((ext_vector_type(8))) _Float16 half8;
typedef __attribute__((ext_vector_type(4))) float f32x4;

typedef const __attribute__((address_space(1))) uint* gas_uint;
typedef __attribute__((address_space(3))) uint* las_uint;

union UH { uint4 u; half8 h; };
__device__ inline half8 as_h8(uint4 v) { UH x; x.u = v; return x.h; }

union H2U { _Float16 h[2]; uint u; };
__device__ inline uint fp16pk(float a, float b) {
    H2U x;
    x.h[0] = (_Float16)a; // v_cvt_f16_f32, RNE
    x.h[1] = (_Float16)b;
    return x.u;
}
__device__ inline void fp16split(float a, _Float16& hi, _Float16& lo) {
    hi = (_Float16)a;
    lo = (_Float16)(a - (float)hi);
}
__device__ inline void pk2(float a, float b, uint& h, uint& l) {
    _Float16 ha, la, hb, lb;
    fp16split(a, ha, la);
    fp16split(b, hb, lb);
    H2U x, y;
    x.h[0] = ha; x.h[1] = hb;
    y.h[0] = la; y.h[1] = lb;
    h = x.u;
    l = y.u;
}

// ---- prep: counter zero + 0.5*||c_k||^2 (fp32 exact) + fp16 coords,
// pre-swizzled per-tile layout. Tile kt (16 k) = 4096 B; row m (k=kt*16+m),
// 16B-group g (d = 8g..8g+7): offset m*256 + ((g^m)<<4).
__global__ __launch_bounds__(256) void prep_kernel(
    const float* __restrict__ coords, float* __restrict__ c2half,
    uint* __restrict__ chi, int* __restrict__ counter) {
    if (blockIdx.x == 0 && threadIdx.x == 0) counter[0] = 0;
    const int k = blockIdx.x * 4 + (threadIdx.x >> 6); // one k-row per wave
    const int dw = threadIdx.x & 63;                   // 2 d per thread
    float a = coords[k * D + 2 * dw], b = coords[k * D + 2 * dw + 1];
    const int g = dw >> 2, sub = dw & 3, kt = k >> 4, m = k & 15;
    char* base = (char*)chi + (size_t)kt * 4096 + m * 256 +
                 ((g ^ m) << 4) + sub * 4;
    *(uint*)base = fp16pk(a, b);
    float s = fmaf(a, a, b * b);
#pragma unroll
    for (int off = 1; off < 64; off <<= 1) s += __shfl_xor(s, off);
    if (dw == 0) c2half[k] = 0.5f * s;
}

// ---- precompute: coordsT[d][k] = coords[k][d] (LDS-tiled, coalesced) ----
__global__ __launch_bounds__(256) void transpose_kernel(
    const float* __restrict__ coords, float* __restrict__ coordsT) {
    __shared__ float tile[64][65];
    const int k0 = blockIdx.x * 64;
    const int d0 = blockIdx.y * 64;
    const int tx = threadIdx.x & 63, ty = threadIdx.x >> 6;
#pragma unroll
    for (int i = 0; i < 64; i += 4)
        tile[ty + i][tx] = coords[(size_t)(k0 + ty + i) * D + d0 + tx];
    __syncthreads();
#pragma unroll
    for (int i = 0; i < 64; i += 4)
        coordsT[(size_t)(d0 + ty + i) * K + k0 + tx] = tile[tx][ty + i];
}

// ---- pass A: fp16 2-term, 16x16x32 MFMA, 1 wave/block, 32 rows/wave,
// KT=16 tiles, wave-private 12KB LDS, NO barriers, counted vmcnt ----
__global__ __launch_bounds__(64, 4) void centroid_mfma_kernel(
    const float* __restrict__ latent, const uint* __restrict__ chi,
    const float* __restrict__ c2, int* __restrict__ out,
    int* __restrict__ counter, int* __restrict__ list) {
    __shared__ __align__(16) char smem[12288]; // 2 x 4K dbuf + 4K c2
    const int l = threadIdx.x;
    const int l15 = l & 15, l4 = l >> 4; // l4 in 0..3
    const int rowbase = blockIdx.x * 32;

    // B-frags (latent, negated, fp16 hi + residual lo) + exact row norms.
    uint4 bh[2][4], bl[2][4];
    float n2[2];
#pragma unroll
    for (int grp = 0; grp < 2; ++grp) {
        const float* rp =
            latent + (size_t)(rowbase + grp * 16 + l15) * D + l4 * 8;
        float s2 = 0.f;
#pragma unroll
        for (int s = 0; s < 4; ++s) {
            float4 u = *(const float4*)(rp + 32 * s);
            float4 v = *(const float4*)(rp + 32 * s + 4);
            s2 += u.x * u.x + u.y * u.y + u.z * u.z + u.w * u.w +
                  v.x * v.x + v.y * v.y + v.z * v.z + v.w * v.w;
            uint h0, o0, h1, o1, h2, o2, h3, o3;
            pk2(-u.x, -u.y, h0, o0);
            pk2(-u.z, -u.w, h1, o1);
            pk2(-v.x, -v.y, h2, o2);
            pk2(-v.z, -v.w, h3, o3);
            bh[grp][s] = make_uint4(h0, h1, h2, h3);
            bl[grp][s] = make_uint4(o0, o1, o2, o3);
        }
        n2[grp] = s2;
    }
#pragma unroll
    for (int grp = 0; grp < 2; ++grp) { // full ||x||^2 on all partner lanes
        n2[grp] += __shfl_xor(n2[grp], 16);
        n2[grp] += __shfl_xor(n2[grp], 32);
    }

    // c2 -> wave-private LDS (4 KB at 8192); same-wave RAW is in-order
    {
        float4* dst = (float4*)(smem + 8192);
        const float4* src = (const float4*)c2;
#pragma unroll
        for (int i = 0; i < 4; ++i) dst[i * 64 + l] = src[i * 64 + l];
    }

    // staging: 4 KB tile per wave, 4 x 1KB global_load_lds
    const char* gsrc0 = (const char*)chi + (l << 4);
#pragma unroll
    for (int i = 0; i < 4; ++i) // tile 0 -> buf 0
        __builtin_amdgcn_global_load_lds((gas_uint)(gsrc0 + i * 1024),
                                         (las_uint)(smem + i * 1024), 16, 0, 0);
#pragma unroll
    for (int i = 0; i < 4; ++i) // tile 1 -> buf 1
        __builtin_amdgcn_global_load_lds((gas_uint)(gsrc0 + 4096 + i * 1024),
                                         (las_uint)(smem + 4096 + i * 1024),
                                         16, 0, 0);

    float m1[2] = {3.4e38f, 3.4e38f};
    float m2[2] = {3.4e38f, 3.4e38f};
    const float* c2l = (const float*)(smem + 8192);
    // acc-init c2 values for tile 0 (register prefetch; rotated each tile)
    float4 cq = *(const float4*)(c2l + l4 * 4);

#pragma unroll 1
    for (int t = 0; t < 64; ++t) {
        const int buf = t & 1;
        // counted wait: tile t's 4 loads retired; t+1's 4 stay in flight
        if (t < 63)
            asm volatile("s_waitcnt vmcnt(4)" ::: "memory");
        else
            asm volatile("s_waitcnt vmcnt(0)" ::: "memory");
        __builtin_amdgcn_sched_barrier(0);

        f32x4 acc[2]; // [grp]: D[k = t*16 + l4*4 + r][row = rowbase+grp*16+l15]
#pragma unroll
        for (int grp = 0; grp < 2; ++grp) {
            acc[grp][0] = cq.x;
            acc[grp][1] = cq.y;
            acc[grp][2] = cq.z;
            acc[grp][3] = cq.w;
        }
        // prefetch next tile's c2 quad (latency hides under MFMA cluster)
        if (t + 1 < 64) cq = *(const float4*)(c2l + (t + 1) * 16 + l4 * 4);

        const char* lhs = smem + buf * 4096;
        __builtin_amdgcn_s_setprio(1);
#pragma unroll
        for (int s = 0; s < 4; ++s) {
            half8 a = *(const half8*)(lhs + l15 * 256 + (((l4 + 4 * s) ^ l15) << 4));
            acc[0] = __builtin_amdgcn_mfma_f32_16x16x32_f16(a, as_h8(bh[0][s]),
                                                            acc[0], 0, 0, 0);
            acc[1] = __builtin_amdgcn_mfma_f32_16x16x32_f16(a, as_h8(bh[1][s]),
                                                            acc[1], 0, 0, 0);
            acc[0] = __builtin_amdgcn_mfma_f32_16x16x32_f16(a, as_h8(bl[0][s]),
                                                            acc[0], 0, 0, 0);
            acc[1] = __builtin_amdgcn_mfma_f32_16x16x32_f16(a, as_h8(bl[1][s]),
                                                            acc[1], 0, 0, 0);
        }
        __builtin_amdgcn_s_setprio(0);
        __builtin_amdgcn_sched_barrier(0);

        // insert: pack k into low 10 mantissa bits, then min/med3 only
        const uint kbase = ((uint)t << 4) + l4 * 4;
#pragma unroll
        for (int r = 0; r < 4; ++r) {
#pragma unroll
            for (int grp = 0; grp < 2; ++grp) {
                uint pb = (__float_as_uint(acc[grp][r]) & 0xFFFFFC00u) |
                          (kbase + r);
                float vp = __uint_as_float(pb);
                m2[grp] = __builtin_amdgcn_fmed3f(vp, m1[grp], m2[grp]);
                m1[grp] = fminf(m1[grp], vp);
            }
        }

        // all LDS reads of this buf complete before DMA overwrites it
        asm volatile("s_waitcnt lgkmcnt(0)" ::: "memory");
        __builtin_amdgcn_sched_barrier(0);
        if (t < 62) {
            const char* gs = gsrc0 + (size_t)(t + 2) * 4096;
            char* ls = smem + buf * 4096;
#pragma unroll
            for (int i = 0; i < 4; ++i)
                __builtin_amdgcn_global_load_lds((gas_uint)(gs + i * 1024),
                                                 (las_uint)(ls + i * 1024),
                                                 16, 0, 0);
        }
    }

    // merge k-partitions: lanes l, l^16, l^32, l^48 hold same rows (l15)
#pragma unroll
    for (int off = 16; off <= 32; off <<= 1) {
#pragma unroll
        for (int grp = 0; grp < 2; ++grp) {
            float om = __shfl_xor(m1[grp], off);
            float o2 = __shfl_xor(m2[grp], off);
            m2[grp] = fminf(fminf(m2[grp], o2), fmaxf(m1[grp], om));
            m1[grp] = fminf(m1[grp], om);
        }
    }

    // lanes 0..15 own rows rowbase + grp*16 + l; per-row sound threshold
    bool flg[2];
    unsigned long long bm[2];
    int total = 0;
#pragma unroll
    for (int grp = 0; grp < 2; ++grp) {
        float eps = 0.0028f * sqrtf(n2[grp]) + 0.015f;
        flg[grp] = (l < 16) && ((m2[grp] - m1[grp]) <= eps);
        bm[grp] = __ballot(flg[grp]);
        total += __popcll(bm[grp]);
    }
    int pos = 0;
    if (l == 0 && total) pos = atomicAdd(counter, total);
    pos = __shfl(pos, 0);
    if (l < 16) {
        int run = pos;
#pragma unroll
        for (int grp = 0; grp < 2; ++grp) {
            out[rowbase + grp * 16 + l] = (int)(__float_as_uint(m1[grp]) & 1023u);
            if (flg[grp])
                list[run + __popcll(bm[grp] & ((1ull << l) - 1ull))] =
                    rowbase + grp * 16 + l;
            run += __popcll(bm[grp]);
        }
    }
}

// ---- pass B: exact fp32 recompute, 4 rows/wave-task, coalesced coordsT ----
__global__ __launch_bounds__(256) void centroid_exact_kernel(
    const float* __restrict__ latent, const float* __restrict__ coordsT,
    const float* __restrict__ c2, const int* __restrict__ cnt_list,
    int* __restrict__ out) {
    const int count = cnt_list[0];
    const int* list = cnt_list + 16;
    const int lane = threadIdx.x & 63;
    const int gw = (blockIdx.x * 256 + threadIdx.x) >> 6;
    const int nwaves = gridDim.x * 4;
    // lane owns k = c*64 + lane, c = 0..15 (coalesced coordsT reads)

    for (int task = gw; task * 4 < count; task += nwaves) {
        const int base = task * 4;
        const int nr = min(4, count - base);
        const float* xp[4];
        int rows[4];
#pragma unroll
        for (int j = 0; j < 4; ++j) {
            int idx = base + (j < nr ? j : nr - 1);
            rows[j] = __builtin_amdgcn_readfirstlane(list[idx]);
            xp[j] = latent + (size_t)rows[j] * D;
        }

        float acc[16][4];
#pragma unroll
        for (int c = 0; c < 16; ++c) {
            float cc = c2[c * 64 + lane];
#pragma unroll
            for (int j = 0; j < 4; ++j) acc[c][j] = cc;
        }

#pragma unroll 1
        for (int d4 = 0; d4 < D / 4; ++d4) {
            float4 xq[4];
#pragma unroll
            for (int j = 0; j < 4; ++j)
                xq[j] = *(const float4*)(xp[j] + 4 * d4);
            float ct[4][16];
#pragma unroll
            for (int dd = 0; dd < 4; ++dd)
#pragma unroll
                for (int c = 0; c < 16; ++c)
                    ct[dd][c] = coordsT[(size_t)(4 * d4 + dd) * K + c * 64 + lane];
#pragma unroll
            for (int dd = 0; dd < 4; ++dd) {
#pragma unroll
                for (int c = 0; c < 16; ++c) {
#pragma unroll
                    for (int j = 0; j < 4; ++j) {
                        float xv = (dd == 0) ? xq[j].x
                                 : (dd == 1) ? xq[j].y
                                 : (dd == 2) ? xq[j].z : xq[j].w;
                        acc[c][j] = fmaf(-xv, ct[dd][c], acc[c][j]);
                    }
                }
            }
        }

#pragma unroll
        for (int j = 0; j < 4; ++j) {
            float m1 = acc[0][j];
            int i1 = lane;
#pragma unroll
            for (int c = 1; c < 16; ++c) {
                const int kk = c * 64 + lane;
                if (acc[c][j] < m1) { m1 = acc[c][j]; i1 = kk; }
            }
#pragma unroll
            for (int off = 1; off < 64; off <<= 1) {
                float om = __shfl_xor(m1, off);
                int oi = __shfl_xor(i1, off);
                if (om < m1 || (om == m1 && oi < i1)) { m1 = om; i1 = oi; }
            }
            if (lane == 0 && j < nr) out[rows[j]] = i1;
        }
    }
}

extern "C" void kernel_launch(void* const* d_in, const int* in_sizes, int n_in,
                              void* d_out, int out_size, void* d_ws, size_t ws_size,
                              hipStream_t stream) {
    const float* latent = (const float*)d_in[0];
    const float* coords = (const float*)d_in[1];
    int* out = (int*)d_out;

    char* ws = (char*)d_ws;
    size_t off = 0;
    float* c2 = (float*)(ws + off); off += 4096;
    uint* chi = (uint*)(ws + off); off += 262144;   // fp16 pre-swizzled
    float* coordsT = (float*)(ws + off); off += 524288;
    int* cnt_list = (int*)(ws + off); off += 64 + 524288;
    int* counter = cnt_list;
    int* list = cnt_list + 16;

    prep_kernel<<<K / 4, 256, 0, stream>>>(coords, c2, chi, counter);
    {
        dim3 g(K / 64, D / 64);
        transpose_kernel<<<g, 256, 0, stream>>>(coords, coordsT);
    }
    // 1 wave/block, 32 rows, KT=16: 4096 blocks, 12KB LDS -> 13 blocks/CU
    centroid_mfma_kernel<<<N / 32, 64, 0, stream>>>(latent, chi, c2, out,
                                                    counter, list);
    centroid_exact_kernel<<<2048, 256, 0, stream>>>(latent, coordsT, c2,
                                                    cnt_list, out);
}

// Round 22
// 145.356 us; speedup vs baseline: 1.1195x; 1.1195x over previous
//
#include <hip/hip_runtime.h>

// CentroidPool: argmin_k ||x_i - c_k||^2, N=131072, K=1024, D=128, fp32.
// = argmin_k (0.5||c_k||^2 - x.c_k).
// 2-term fp16 latent split (sound eps_row = 0.0028*||x||+0.015); certify-
// or-recompute: flagged rows -> exact fp32 pass B.
// r21 postmortem: 1-wave blocks cap at ~7-8 workgroups/CU regardless of
// LDS (12KB fit 13 blocks, occupancy stayed 21%); KT=16 doubled per-tile
// overhead at unchanged wave count -> MfmaUtil 23%.
// r22: 4-wave blocks (256 thr), each wave PRIVATE (own 32 rows, own
// 2x4KB dbuf, own loop) -- still ZERO barriers. 36KB LDS -> 4 blocks/CU
// = 16 waves/CU, past the wg cap. c2 written redundantly by every wave
// (benign same-value race; same-wave RAW is ordered).

constexpr int N = 131072;
constexpr int K = 1024;
constexpr int D = 128;

typedef __attribute__((ext_vector_type(8))) _Float16 half8;
typedef __attribute__((ext_vector_type(4))) float f32x4;

typedef const __attribute__((address_space(1))) uint* gas_uint;
typedef __attribute__((address_space(3))) uint* las_uint;

union UH { uint4 u; half8 h; };
__device__ inline half8 as_h8(uint4 v) { UH x; x.u = v; return x.h; }

union H2U { _Float16 h[2]; uint u; };
__device__ inline uint fp16pk(float a, float b) {
    H2U x;
    x.h[0] = (_Float16)a; // v_cvt_f16_f32, RNE
    x.h[1] = (_Float16)b;
    return x.u;
}
__device__ inline void fp16split(float a, _Float16& hi, _Float16& lo) {
    hi = (_Float16)a;
    lo = (_Float16)(a - (float)hi);
}
__device__ inline void pk2(float a, float b, uint& h, uint& l) {
    _Float16 ha, la, hb, lb;
    fp16split(a, ha, la);
    fp16split(b, hb, lb);
    H2U x, y;
    x.h[0] = ha; x.h[1] = hb;
    y.h[0] = la; y.h[1] = lb;
    h = x.u;
    l = y.u;
}

// ---- prep: counter zero + 0.5*||c_k||^2 (fp32 exact) + fp16 coords,
// pre-swizzled per-tile layout. Tile kt (16 k) = 4096 B; row m (k=kt*16+m),
// 16B-group g (d = 8g..8g+7): offset m*256 + ((g^m)<<4).
__global__ __launch_bounds__(256) void prep_kernel(
    const float* __restrict__ coords, float* __restrict__ c2half,
    uint* __restrict__ chi, int* __restrict__ counter) {
    if (blockIdx.x == 0 && threadIdx.x == 0) counter[0] = 0;
    const int k = blockIdx.x * 4 + (threadIdx.x >> 6); // one k-row per wave
    const int dw = threadIdx.x & 63;                   // 2 d per thread
    float a = coords[k * D + 2 * dw], b = coords[k * D + 2 * dw + 1];
    const int g = dw >> 2, sub = dw & 3, kt = k >> 4, m = k & 15;
    char* base = (char*)chi + (size_t)kt * 4096 + m * 256 +
                 ((g ^ m) << 4) + sub * 4;
    *(uint*)base = fp16pk(a, b);
    float s = fmaf(a, a, b * b);
#pragma unroll
    for (int off = 1; off < 64; off <<= 1) s += __shfl_xor(s, off);
    if (dw == 0) c2half[k] = 0.5f * s;
}

// ---- precompute: coordsT[d][k] = coords[k][d] (LDS-tiled, coalesced) ----
__global__ __launch_bounds__(256) void transpose_kernel(
    const float* __restrict__ coords, float* __restrict__ coordsT) {
    __shared__ float tile[64][65];
    const int k0 = blockIdx.x * 64;
    const int d0 = blockIdx.y * 64;
    const int tx = threadIdx.x & 63, ty = threadIdx.x >> 6;
#pragma unroll
    for (int i = 0; i < 64; i += 4)
        tile[ty + i][tx] = coords[(size_t)(k0 + ty + i) * D + d0 + tx];
    __syncthreads();
#pragma unroll
    for (int i = 0; i < 64; i += 4)
        coordsT[(size_t)(d0 + ty + i) * K + k0 + tx] = tile[tx][ty + i];
}

// ---- pass A: fp16 2-term, 16x16x32 MFMA, 4 PRIVATE waves/block,
// 32 rows/wave, KT=16, per-wave 8KB dbuf, NO barriers, counted vmcnt ----
__global__ __launch_bounds__(256, 4) void centroid_mfma_kernel(
    const float* __restrict__ latent, const uint* __restrict__ chi,
    const float* __restrict__ c2, int* __restrict__ out,
    int* __restrict__ counter, int* __restrict__ list) {
    __shared__ __align__(16) char smem[36864]; // 4 waves x 8K dbuf + 4K c2
    const int l = threadIdx.x & 63, w = threadIdx.x >> 6;
    const int l15 = l & 15, l4 = l >> 4; // l4 in 0..3
    const int rowbase = blockIdx.x * 128 + w * 32;
    char* const wbuf = smem + w * 8192; // this wave's private double-buffer

    // B-frags (latent, negated, fp16 hi + residual lo) + exact row norms.
    uint4 bh[2][4], bl[2][4];
    float n2[2];
#pragma unroll
    for (int grp = 0; grp < 2; ++grp) {
        const float* rp =
            latent + (size_t)(rowbase + grp * 16 + l15) * D + l4 * 8;
        float s2 = 0.f;
#pragma unroll
        for (int s = 0; s < 4; ++s) {
            float4 u = *(const float4*)(rp + 32 * s);
            float4 v = *(const float4*)(rp + 32 * s + 4);
            s2 += u.x * u.x + u.y * u.y + u.z * u.z + u.w * u.w +
                  v.x * v.x + v.y * v.y + v.z * v.z + v.w * v.w;
            uint h0, o0, h1, o1, h2, o2, h3, o3;
            pk2(-u.x, -u.y, h0, o0);
            pk2(-u.z, -u.w, h1, o1);
            pk2(-v.x, -v.y, h2, o2);
            pk2(-v.z, -v.w, h3, o3);
            bh[grp][s] = make_uint4(h0, h1, h2, h3);
            bl[grp][s] = make_uint4(o0, o1, o2, o3);
        }
        n2[grp] = s2;
    }
#pragma unroll
    for (int grp = 0; grp < 2; ++grp) { // full ||x||^2 on all partner lanes
        n2[grp] += __shfl_xor(n2[grp], 16);
        n2[grp] += __shfl_xor(n2[grp], 32);
    }

    // c2 -> LDS (4 KB at 32768). Every wave writes the full table
    // (same values -> benign race; own write guarantees own visibility).
    {
        float4* dst = (float4*)(smem + 32768);
        const float4* src = (const float4*)c2;
#pragma unroll
        for (int i = 0; i < 4; ++i) dst[i * 64 + l] = src[i * 64 + l];
    }

    // staging: 4 KB tile per wave, 4 x 1KB global_load_lds
    const char* gsrc0 = (const char*)chi + (l << 4);
#pragma unroll
    for (int i = 0; i < 4; ++i) // tile 0 -> buf 0
        __builtin_amdgcn_global_load_lds((gas_uint)(gsrc0 + i * 1024),
                                         (las_uint)(wbuf + i * 1024), 16, 0, 0);
#pragma unroll
    for (int i = 0; i < 4; ++i) // tile 1 -> buf 1
        __builtin_amdgcn_global_load_lds((gas_uint)(gsrc0 + 4096 + i * 1024),
                                         (las_uint)(wbuf + 4096 + i * 1024),
                                         16, 0, 0);

    float m1[2] = {3.4e38f, 3.4e38f};
    float m2[2] = {3.4e38f, 3.4e38f};
    const float* c2l = (const float*)(smem + 32768);
    // acc-init c2 quad for tile 0 (register prefetch; rotated each tile)
    float4 cq = *(const float4*)(c2l + l4 * 4);

#pragma unroll 1
    for (int t = 0; t < 64; ++t) {
        const int buf = t & 1;
        // counted wait: tile t's 4 loads retired; t+1's 4 stay in flight
        if (t < 63)
            asm volatile("s_waitcnt vmcnt(4)" ::: "memory");
        else
            asm volatile("s_waitcnt vmcnt(0)" ::: "memory");
        __builtin_amdgcn_sched_barrier(0);

        f32x4 acc[2]; // [grp]: D[k = t*16 + l4*4 + r][row = rowbase+grp*16+l15]
#pragma unroll
        for (int grp = 0; grp < 2; ++grp) {
            acc[grp][0] = cq.x;
            acc[grp][1] = cq.y;
            acc[grp][2] = cq.z;
            acc[grp][3] = cq.w;
        }
        // prefetch next tile's c2 quad (latency hides under MFMA cluster)
        if (t + 1 < 64) cq = *(const float4*)(c2l + (t + 1) * 16 + l4 * 4);

        const char* lhs = wbuf + buf * 4096;
        __builtin_amdgcn_s_setprio(1);
#pragma unroll
        for (int s = 0; s < 4; ++s) {
            half8 a = *(const half8*)(lhs + l15 * 256 + (((l4 + 4 * s) ^ l15) << 4));
            acc[0] = __builtin_amdgcn_mfma_f32_16x16x32_f16(a, as_h8(bh[0][s]),
                                                            acc[0], 0, 0, 0);
            acc[1] = __builtin_amdgcn_mfma_f32_16x16x32_f16(a, as_h8(bh[1][s]),
                                                            acc[1], 0, 0, 0);
            acc[0] = __builtin_amdgcn_mfma_f32_16x16x32_f16(a, as_h8(bl[0][s]),
                                                            acc[0], 0, 0, 0);
            acc[1] = __builtin_amdgcn_mfma_f32_16x16x32_f16(a, as_h8(bl[1][s]),
                                                            acc[1], 0, 0, 0);
        }
        __builtin_amdgcn_s_setprio(0);
        __builtin_amdgcn_sched_barrier(0);

        // insert: pack k into low 10 mantissa bits, then min/med3 only
        const uint kbase = ((uint)t << 4) + l4 * 4;
#pragma unroll
        for (int r = 0; r < 4; ++r) {
#pragma unroll
            for (int grp = 0; grp < 2; ++grp) {
                uint pb = (__float_as_uint(acc[grp][r]) & 0xFFFFFC00u) |
                          (kbase + r);
                float vp = __uint_as_float(pb);
                m2[grp] = __builtin_amdgcn_fmed3f(vp, m1[grp], m2[grp]);
                m1[grp] = fminf(m1[grp], vp);
            }
        }

        // all LDS reads of this buf complete before DMA overwrites it
        asm volatile("s_waitcnt lgkmcnt(0)" ::: "memory");
        __builtin_amdgcn_sched_barrier(0);
        if (t < 62) {
            const char* gs = gsrc0 + (size_t)(t + 2) * 4096;
            char* ls = wbuf + buf * 4096;
#pragma unroll
            for (int i = 0; i < 4; ++i)
                __builtin_amdgcn_global_load_lds((gas_uint)(gs + i * 1024),
                                                 (las_uint)(ls + i * 1024),
                                                 16, 0, 0);
        }
    }

    // merge k-partitions: lanes l, l^16, l^32, l^48 hold same rows (l15)
#pragma unroll
    for (int off = 16; off <= 32; off <<= 1) {
#pragma unroll
        for (int grp = 0; grp < 2; ++grp) {
            float om = __shfl_xor(m1[grp], off);
            float o2 = __shfl_xor(m2[grp], off);
            m2[grp] = fminf(fminf(m2[grp], o2), fmaxf(m1[grp], om));
            m1[grp] = fminf(m1[grp], om);
        }
    }

    // lanes 0..15 own rows rowbase + grp*16 + l; per-row sound threshold
    bool flg[2];
    unsigned long long bm[2];
    int total = 0;
#pragma unroll
    for (int grp = 0; grp < 2; ++grp) {
        float eps = 0.0028f * sqrtf(n2[grp]) + 0.015f;
        flg[grp] = (l < 16) && ((m2[grp] - m1[grp]) <= eps);
        bm[grp] = __ballot(flg[grp]);
        total += __popcll(bm[grp]);
    }
    int pos = 0;
    if (l == 0 && total) pos = atomicAdd(counter, total);
    pos = __shfl(pos, 0);
    if (l < 16) {
        int run = pos;
#pragma unroll
        for (int grp = 0; grp < 2; ++grp) {
            out[rowbase + grp * 16 + l] = (int)(__float_as_uint(m1[grp]) & 1023u);
            if (flg[grp])
                list[run + __popcll(bm[grp] & ((1ull << l) - 1ull))] =
                    rowbase + grp * 16 + l;
            run += __popcll(bm[grp]);
        }
    }
}

// ---- pass B: exact fp32 recompute, 4 rows/wave-task, coalesced coordsT ----
__global__ __launch_bounds__(256) void centroid_exact_kernel(
    const float* __restrict__ latent, const float* __restrict__ coordsT,
    const float* __restrict__ c2, const int* __restrict__ cnt_list,
    int* __restrict__ out) {
    const int count = cnt_list[0];
    const int* list = cnt_list + 16;
    const int lane = threadIdx.x & 63;
    const int gw = (blockIdx.x * 256 + threadIdx.x) >> 6;
    const int nwaves = gridDim.x * 4;
    // lane owns k = c*64 + lane, c = 0..15 (coalesced coordsT reads)

    for (int task = gw; task * 4 < count; task += nwaves) {
        const int base = task * 4;
        const int nr = min(4, count - base);
        const float* xp[4];
        int rows[4];
#pragma unroll
        for (int j = 0; j < 4; ++j) {
            int idx = base + (j < nr ? j : nr - 1);
            rows[j] = __builtin_amdgcn_readfirstlane(list[idx]);
            xp[j] = latent + (size_t)rows[j] * D;
        }

        float acc[16][4];
#pragma unroll
        for (int c = 0; c < 16; ++c) {
            float cc = c2[c * 64 + lane];
#pragma unroll
            for (int j = 0; j < 4; ++j) acc[c][j] = cc;
        }

#pragma unroll 1
        for (int d4 = 0; d4 < D / 4; ++d4) {
            float4 xq[4];
#pragma unroll
            for (int j = 0; j < 4; ++j)
                xq[j] = *(const float4*)(xp[j] + 4 * d4);
            float ct[4][16];
#pragma unroll
            for (int dd = 0; dd < 4; ++dd)
#pragma unroll
                for (int c = 0; c < 16; ++c)
                    ct[dd][c] = coordsT[(size_t)(4 * d4 + dd) * K + c * 64 + lane];
#pragma unroll
            for (int dd = 0; dd < 4; ++dd) {
#pragma unroll
                for (int c = 0; c < 16; ++c) {
#pragma unroll
                    for (int j = 0; j < 4; ++j) {
                        float xv = (dd == 0) ? xq[j].x
                                 : (dd == 1) ? xq[j].y
                                 : (dd == 2) ? xq[j].z : xq[j].w;
                        acc[c][j] = fmaf(-xv, ct[dd][c], acc[c][j]);
                    }
                }
            }
        }

#pragma unroll
        for (int j = 0; j < 4; ++j) {
            float m1 = acc[0][j];
            int i1 = lane;
#pragma unroll
            for (int c = 1; c < 16; ++c) {
                const int kk = c * 64 + lane;
                if (acc[c][j] < m1) { m1 = acc[c][j]; i1 = kk; }
            }
#pragma unroll
            for (int off = 1; off < 64; off <<= 1) {
                float om = __shfl_xor(m1, off);
                int oi = __shfl_xor(i1, off);
                if (om < m1 || (om == m1 && oi < i1)) { m1 = om; i1 = oi; }
            }
            if (lane == 0 && j < nr) out[rows[j]] = i1;
        }
    }
}

extern "C" void kernel_launch(void* const* d_in, const int* in_sizes, int n_in,
                              void* d_out, int out_size, void* d_ws, size_t ws_size,
                              hipStream_t stream) {
    const float* latent = (const float*)d_in[0];
    const float* coords = (const float*)d_in[1];
    int* out = (int*)d_out;

    char* ws = (char*)d_ws;
    size_t off = 0;
    float* c2 = (float*)(ws + off); off += 4096;
    uint* chi = (uint*)(ws + off); off += 262144;   // fp16 pre-swizzled
    float* coordsT = (float*)(ws + off); off += 524288;
    int* cnt_list = (int*)(ws + off); off += 64 + 524288;
    int* counter = cnt_list;
    int* list = cnt_list + 16;

    prep_kernel<<<K / 4, 256, 0, stream>>>(coords, c2, chi, counter);
    {
        dim3 g(K / 64, D / 64);
        transpose_kernel<<<g, 256, 0, stream>>>(coords, coordsT);
    }
    // 4 private waves/block, 128 rows/block: 1024 blocks, 36KB LDS
    // -> 4 blocks/CU = 16 waves/CU, zero barriers
    centroid_mfma_kernel<<<N / 128, 256, 0, stream>>>(latent, chi, c2, out,
                                                      counter, list);
    centroid_exact_kernel<<<2048, 256, 0, stream>>>(latent, coordsT, c2,
                                                    cnt_list, out);
}